// Round 1
// baseline (1213.763 us; speedup 1.0000x reference)
//
#include <hip/hip_runtime.h>
#include <hip/hip_bf16.h>

// ---------------------------------------------------------------------------
// SharedSpecialistMoEFFN on MI355X (gfx950) — round 4
//
// R3 post-mortem: no spill (WRITE=200MB = H exactly), bank conflicts 0, but
// MfmaUtil 26% / HBM 16% -> schedule-bound. The K-loop was the m97 structure:
// stage -> vmcnt(0) -> barrier -> compute = full drain every K-step, no
// load/compute overlap (and only 16 K-steps at K=1024 to amortize it).
// R4: port GEMM to the 256x256 deep-pipeline template: 8 waves (512 thr),
// BK=64, 128 KiB double-buffered LDS, RAW s_barrier (no __syncthreads drain),
// COUNTED s_waitcnt vmcnt(4) so next-tile prefetch stays in flight across the
// barrier, s_setprio(1) around the MFMA cluster. Per K-tile: issue next-A,
// vmcnt(4), barrier, {24 ds_read_b128 + 64 MFMA + issue next-B}, lgkmcnt(0),
// barrier.  XOR k-chunk swizzle and C/D layout carried over unchanged.
// ---------------------------------------------------------------------------

#define D_MODEL 1024
#define D_FF    4096
#define N_EXP   8
#define T_TOK   8192
#define BK      64

typedef _Float16 half8  __attribute__((ext_vector_type(8)));
typedef _Float16 half4v __attribute__((ext_vector_type(4)));
typedef float    floatx4 __attribute__((ext_vector_type(4)));

__device__ __forceinline__ float gelu_exact(float x) {
  return 0.5f * x * (1.0f + erff(x * 0.70710678118654752f));
}

__device__ __forceinline__ void gld_lds16(const _Float16* g, _Float16* l) {
  __builtin_amdgcn_global_load_lds(
      (const __attribute__((address_space(1))) void*)g,
      (__attribute__((address_space(3))) void*)l, 16, 0, 0);
}

// ---------------------------------------------------------------- converts
__global__ void convert_f32_f16(const float* __restrict__ src,
                                _Float16* __restrict__ dst, int n4) {
  int i = blockIdx.x * blockDim.x + threadIdx.x;
  if (i >= n4) return;
  float4 v = ((const float4*)src)[i];
  half4v h;
  h[0] = (_Float16)v.x; h[1] = (_Float16)v.y;
  h[2] = (_Float16)v.z; h[3] = (_Float16)v.w;
  ((half4v*)dst)[i] = h;
}

// z=0: shared weight, z>=1: expert z-1.  src fp32 [R][C] -> dst fp16 [C][R]
__global__ void transpose_convert9(const float* __restrict__ srcSh,
                                   const float* __restrict__ srcEx,
                                   _Float16* __restrict__ dst, int R, int C) {
  const size_t msz = (size_t)R * C;
  const float* src = (blockIdx.z == 0) ? srcSh : srcEx + msz * (blockIdx.z - 1);
  _Float16* d = dst + msz * blockIdx.z;
  __shared__ float tile[32][33];
  int c0 = blockIdx.x * 32, r0 = blockIdx.y * 32;
  int tx = threadIdx.x, ty = threadIdx.y;   // block (32, 8)
#pragma unroll
  for (int i = 0; i < 4; ++i)
    tile[ty + i * 8][tx] = src[(size_t)(r0 + ty + i * 8) * C + c0 + tx];
  __syncthreads();
#pragma unroll
  for (int i = 0; i < 4; ++i)
    d[(size_t)(c0 + ty + i * 8) * R + r0 + tx] = (_Float16)tile[tx][ty + i * 8];
}

// ---------------------------------------------------------------- router
__global__ void router_kernel(const float* __restrict__ x,
                              const float* __restrict__ rw,
                              const float* __restrict__ rb,
                              int* __restrict__ sel_idx,
                              float* __restrict__ sel_w,
                              int* __restrict__ counts) {
  int lane = threadIdx.x & 63;
  int t = blockIdx.x * 4 + (threadIdx.x >> 6);
  const float* xr = x + (size_t)t * D_MODEL;
  float acc[N_EXP];
#pragma unroll
  for (int e = 0; e < N_EXP; ++e) acc[e] = 0.f;
  for (int k = lane; k < D_MODEL; k += 64) {
    float xv = xr[k];
    const float* w = rw + (size_t)k * N_EXP;
#pragma unroll
    for (int e = 0; e < N_EXP; ++e) acc[e] += xv * w[e];
  }
#pragma unroll
  for (int off = 32; off > 0; off >>= 1) {
#pragma unroll
    for (int e = 0; e < N_EXP; ++e)
      acc[e] += __shfl_down(acc[e], off, 64);
  }
  if (lane == 0) {
    float mx = -1e30f;
#pragma unroll
    for (int e = 0; e < N_EXP; ++e) { acc[e] += rb[e]; mx = fmaxf(mx, acc[e]); }
    float p[N_EXP], s = 0.f;
#pragma unroll
    for (int e = 0; e < N_EXP; ++e) { p[e] = expf(acc[e] - mx); s += p[e]; }
    float inv = 1.f / s;
#pragma unroll
    for (int e = 0; e < N_EXP; ++e) p[e] *= inv;
    int i0 = 0; float p0 = p[0];
#pragma unroll
    for (int e = 1; e < N_EXP; ++e) if (p[e] > p0) { p0 = p[e]; i0 = e; }
    int i1 = -1; float p1 = -1.f;
#pragma unroll
    for (int e = 0; e < N_EXP; ++e)
      if (e != i0 && p[e] > p1) { p1 = p[e]; i1 = e; }
    float s2 = p0 + p1 + 1e-9f;
    sel_idx[2 * t] = i0; sel_idx[2 * t + 1] = i1;
    sel_w[2 * t] = p0 / s2; sel_w[2 * t + 1] = p1 / s2;
    atomicAdd(&counts[i0 * 32], 1);
    atomicAdd(&counts[i1 * 32], 1);
  }
}

__global__ void scan_kernel(const int* __restrict__ counts,
                            int* __restrict__ offsets,
                            int* __restrict__ cursor) {
  if (threadIdx.x == 0) {
    int s = 0;
    for (int e = 0; e < N_EXP; ++e) {
      offsets[e] = s; cursor[e * 32] = s; s += counts[e * 32];
    }
    offsets[N_EXP] = s;
  }
}

__global__ void assign_kernel(const int* __restrict__ sel_idx,
                              int* __restrict__ cursor,
                              int* __restrict__ rows,
                              int* __restrict__ inv) {
  int t = blockIdx.x * blockDim.x + threadIdx.x;
  if (t >= T_TOK) return;
#pragma unroll
  for (int k = 0; k < 2; ++k) {
    int e = sel_idx[2 * t + k];
    int pos = atomicAdd(&cursor[e * 32], 1);
    rows[pos] = t;
    inv[2 * t + k] = pos;
  }
}

// ---------------------------------------------------------------- GEMM
// 256x256 tile, BK=64, 512 threads = 8 waves (2M x 4N), per-wave 128x64 out.
// LDS 128 KiB: double-buffered A[256][64] + B[256][64] fp16 (1 block/CU).
// Pipeline per K-tile t (buf = t&1):
//   issue A-stage of t+1 -> buf^1            (4 x global_load_lds dwordx4)
//   s_waitcnt vmcnt(4)                       (tile t fully landed; t+1 A in flight)
//   s_barrier                                (cross-wave visibility)
//   ks=0: 12 ds_read_b128, setprio(1), 32 MFMA, setprio(0); issue B-stage t+1
//   ks=1: 12 ds_read_b128, setprio(1), 32 MFMA, setprio(0)
//   s_waitcnt lgkmcnt(0); s_barrier          (buf free for t+2's stage)
// vmcnt ledger at the wait: cur-tile 8 (oldest) + next-A 4 = 12 outstanding;
// vmcnt(4) retires exactly the current tile. Last iter uses vmcnt(0).
template <int PHASE>
__global__ __launch_bounds__(512, 2) void gemm_kernel(
    const _Float16* __restrict__ A, const _Float16* __restrict__ Wt,
    const float* __restrict__ biasSh, const float* __restrict__ biasEx,
    _Float16* __restrict__ Hout, float* __restrict__ out,
    float* __restrict__ Yexp, const int* __restrict__ rows,
    const int* __restrict__ counts, const int* __restrict__ offsets) {
  constexpr int K = (PHASE == 1) ? D_MODEL : D_FF;
  constexpr int N = (PHASE == 1) ? D_FF : D_MODEL;
  constexpr int NT = K / BK;
  const int z = blockIdx.z;
  int M = T_TOK, offs = 0;
  if (z > 0) {
    M = counts[(z - 1) * 32];
    offs = offsets[z - 1];
    if ((int)blockIdx.y * 256 >= M) return;   // uniform early-exit
  }
  const int tid = threadIdx.x, lane = tid & 63, wid = tid >> 6;
  const int m0 = blockIdx.y * 256, n0 = blockIdx.x * 256;
  const _Float16* Wz = Wt + (size_t)z * N * K;

  __shared__ __align__(16) _Float16 As[2 * 256 * BK];   // 64 KiB
  __shared__ __align__(16) _Float16 Bs[2 * 256 * BK];   // 64 KiB

  // staging: 32 groups of 8 rows x 8 k-chunks(16B); wave w fills groups
  // w*4..w*4+3. lane i -> row sub=i>>3, physical slot p=i&7 holding GLOBAL
  // k-chunk g = p ^ sub (XOR swizzle; read side uses slot = c ^ (r&7)).
  const int sub = lane >> 3, pp = lane & 7, g = pp ^ sub;

  const _Float16* aS[4];
  const _Float16* bS[4];
#pragma unroll
  for (int j = 0; j < 4; ++j) {
    int r = m0 + wid * 32 + j * 8 + sub;
    size_t gr;
    if (z == 0) {
      gr = (size_t)r;
    } else {
      int rc = r < M ? r : M - 1;
      if constexpr (PHASE == 1) gr = (size_t)rows[offs + rc];
      else                      gr = (size_t)(T_TOK + offs + rc);
    }
    aS[j] = A + gr * K + g * 8;
    bS[j] = Wz + (size_t)(n0 + wid * 32 + j * 8 + sub) * K + g * 8;
  }

  // prologue: stage K-tile 0 into buffer 0 (A first, then B — order matters
  // for the vmcnt ledger).
#pragma unroll
  for (int j = 0; j < 4; ++j) {
    gld_lds16(aS[j], As + (wid * 4 + j) * 512); aS[j] += BK;
  }
#pragma unroll
  for (int j = 0; j < 4; ++j) {
    gld_lds16(bS[j], Bs + (wid * 4 + j) * 512); bS[j] += BK;
  }

  floatx4 acc[8][4] = {};
  const int wm = wid >> 2, wn = wid & 3;      // 2 x 4 wave grid
  const int lr = lane & 15, qd = lane >> 4;
  const int xm = lr & 7;                      // row&7 == lr&7 for all frags

#pragma unroll 2
  for (int t = 0; t < NT; ++t) {
    _Float16* Ac = As + (t & 1) * (256 * BK);
    _Float16* Bc = Bs + (t & 1) * (256 * BK);
    _Float16* An = As + ((t & 1) ^ 1) * (256 * BK);
    _Float16* Bn = Bs + ((t & 1) ^ 1) * (256 * BK);
    if (t + 1 < NT) {
#pragma unroll
      for (int j = 0; j < 4; ++j) {
        gld_lds16(aS[j], An + (wid * 4 + j) * 512); aS[j] += BK;
      }
      asm volatile("s_waitcnt vmcnt(4)" ::: "memory");
    } else {
      asm volatile("s_waitcnt vmcnt(0)" ::: "memory");
    }
    __builtin_amdgcn_s_barrier();
    asm volatile("" ::: "memory");
    __builtin_amdgcn_sched_barrier(0);
#pragma unroll
    for (int ks = 0; ks < 2; ++ks) {
      half8 af[8], bf[4];
      const int slot = (ks * 4 + qd) ^ xm;
#pragma unroll
      for (int mi = 0; mi < 8; ++mi)
        af[mi] = *(const half8*)(Ac + (wm * 128 + mi * 16 + lr) * BK + slot * 8);
#pragma unroll
      for (int ni = 0; ni < 4; ++ni)
        bf[ni] = *(const half8*)(Bc + (wn * 64 + ni * 16 + lr) * BK + slot * 8);
      __builtin_amdgcn_s_setprio(1);
#pragma unroll
      for (int mi = 0; mi < 8; ++mi)
#pragma unroll
        for (int ni = 0; ni < 4; ++ni)
          acc[mi][ni] = __builtin_amdgcn_mfma_f32_16x16x32_f16(
              af[mi], bf[ni], acc[mi][ni], 0, 0, 0);
      __builtin_amdgcn_s_setprio(0);
      if (ks == 0 && t + 1 < NT) {
#pragma unroll
        for (int j = 0; j < 4; ++j) {
          gld_lds16(bS[j], Bn + (wid * 4 + j) * 512); bS[j] += BK;
        }
      }
    }
    asm volatile("s_waitcnt lgkmcnt(0)" ::: "memory");
    __builtin_amdgcn_sched_barrier(0);
    __builtin_amdgcn_s_barrier();
  }

  // epilogue: C/D layout col=lane&15, row=quad*4+reg (R1-verified)
  const float* be = (z == 0) ? biasSh : biasEx + (size_t)(z - 1) * N;
#pragma unroll
  for (int mi = 0; mi < 8; ++mi) {
#pragma unroll
    for (int ni = 0; ni < 4; ++ni) {
      floatx4 v = acc[mi][ni];
#pragma unroll
      for (int r4 = 0; r4 < 4; ++r4) {
        const int lrow = m0 + wm * 128 + mi * 16 + qd * 4 + r4;  // row in segment
        const int col = n0 + wn * 64 + ni * 16 + lr;
        const float val = v[r4] + be[col];
        if constexpr (PHASE == 1) {
          if (z == 0) {
            Hout[(size_t)lrow * N + col] = (_Float16)gelu_exact(val);
          } else if (lrow < M) {
            Hout[(size_t)(T_TOK + offs + lrow) * N + col] =
                (_Float16)gelu_exact(val);
          }
        } else {
          if (z == 0) {
            out[(size_t)lrow * N + col] = val;
          } else if (lrow < M) {
            Yexp[(size_t)(offs + lrow) * N + col] = val;
          }
        }
      }
    }
  }
}

// ---------------------------------------------------------------- combine
// out[t] = out[t] (shared FFN2) + w0*Yexp[p0] + w1*Yexp[p1]
__global__ void combine_kernel(float* __restrict__ out,
                               const float* __restrict__ Yexp,
                               const int* __restrict__ inv,
                               const float* __restrict__ selw) {
  const int t = blockIdx.x;
  const int c = threadIdx.x * 4;
  const int p0 = inv[2 * t], p1 = inv[2 * t + 1];
  const float w0 = selw[2 * t], w1 = selw[2 * t + 1];
  float4 o = *(float4*)(out + (size_t)t * D_MODEL + c);
  const float4 a = *(const float4*)(Yexp + (size_t)p0 * D_MODEL + c);
  const float4 b = *(const float4*)(Yexp + (size_t)p1 * D_MODEL + c);
  o.x += w0 * a.x + w1 * b.x;
  o.y += w0 * a.y + w1 * b.y;
  o.z += w0 * a.z + w1 * b.z;
  o.w += w0 * a.w + w1 * b.w;
  *(float4*)(out + (size_t)t * D_MODEL + c) = o;
}

// ---------------------------------------------------------------- launch
extern "C" void kernel_launch(void* const* d_in, const int* in_sizes, int n_in,
                              void* d_out, int out_size, void* d_ws,
                              size_t ws_size, hipStream_t stream) {
  const float* x   = (const float*)d_in[0];
  const float* sw1 = (const float*)d_in[1];
  const float* sb1 = (const float*)d_in[2];
  const float* sw2 = (const float*)d_in[3];
  const float* sb2 = (const float*)d_in[4];
  const float* rw  = (const float*)d_in[5];
  const float* rb  = (const float*)d_in[6];
  const float* ew1 = (const float*)d_in[7];
  const float* eb1 = (const float*)d_in[8];
  const float* ew2 = (const float*)d_in[9];
  const float* eb2 = (const float*)d_in[10];
  float* out = (float*)d_out;

  char* ws = (char*)d_ws;
  size_t off = 0;
  auto alloc = [&](size_t bytes) {
    void* p = ws + off;
    off += (bytes + 255) & ~(size_t)255;
    return p;
  };
  _Float16* xb  = (_Float16*)alloc((size_t)T_TOK * D_MODEL * 2);        // 16 MB
  _Float16* w2t = (_Float16*)alloc((size_t)9 * D_MODEL * D_FF * 2);     // 72 MB
  _Float16* H   = (_Float16*)alloc((size_t)3 * T_TOK * D_FF * 2);       // 201 MB
  _Float16* w1t = (_Float16*)alloc((size_t)9 * D_FF * D_MODEL * 2);     // 72 MB
  float* Yexp   = (float*)w1t;  // alias: w1t dead after FFN1, Yexp 67 MB
  int*   sel_idx = (int*)alloc((size_t)T_TOK * 2 * 4);
  float* sel_w   = (float*)alloc((size_t)T_TOK * 2 * 4);
  int*   rows    = (int*)alloc((size_t)2 * T_TOK * 4);
  int*   inv     = (int*)alloc((size_t)2 * T_TOK * 4);
  int*   counts  = (int*)alloc(N_EXP * 32 * 4);
  int*   offsets = (int*)alloc(16 * 4);
  int*   cursor  = (int*)alloc(N_EXP * 32 * 4);
  (void)ws_size; (void)in_sizes; (void)n_in; (void)out_size;

  hipMemsetAsync(counts, 0, N_EXP * 32 * 4, stream);

  convert_f32_f16<<<(T_TOK * D_MODEL / 4 + 255) / 256, 256, 0, stream>>>(
      x, xb, T_TOK * D_MODEL / 4);
  dim3 tb(32, 8);
  // W1: [1024][4096] -> [4096][1024];  W2: [4096][1024] -> [1024][4096]
  transpose_convert9<<<dim3(D_FF / 32, D_MODEL / 32, 9), tb, 0, stream>>>(
      sw1, ew1, w1t, D_MODEL, D_FF);
  transpose_convert9<<<dim3(D_MODEL / 32, D_FF / 32, 9), tb, 0, stream>>>(
      sw2, ew2, w2t, D_FF, D_MODEL);

  router_kernel<<<T_TOK / 4, 256, 0, stream>>>(x, rw, rb, sel_idx, sel_w, counts);
  scan_kernel<<<1, 64, 0, stream>>>(counts, offsets, cursor);
  assign_kernel<<<T_TOK / 256, 256, 0, stream>>>(sel_idx, cursor, rows, inv);

  gemm_kernel<1><<<dim3(D_FF / 256, T_TOK / 256, 9), 512, 0, stream>>>(
      xb, w1t, sb1, eb1, H, nullptr, nullptr, rows, counts, offsets);
  gemm_kernel<2><<<dim3(D_MODEL / 256, T_TOK / 256, 9), 512, 0, stream>>>(
      H, w2t, sb2, eb2, nullptr, out, Yexp, rows, counts, offsets);

  combine_kernel<<<T_TOK, 256, 0, stream>>>(out, Yexp, inv, sel_w);
}